// Round 8
// baseline (260.179 us; speedup 1.0000x reference)
//
#include <hip/hip_runtime.h>
#include <hip/hip_bf16.h>

// Problem constants
#define B_  16
#define T_  1024
#define C_  1024
#define H_  16
#define KW_ 31
#define M_  (B_ * T_)     // 16384 rows
#define N1_ (2 * C_)      // 2048  (GEMM1 N)
#define K1_ C_            // 1024  (GEMM1 K)
#define N2_ C_            // 1024  (GEMM2 N)
#define K2_ (2 * C_)      // 2048  (GEMM2 K)

typedef __attribute__((ext_vector_type(8))) short bf16x8;
typedef __attribute__((ext_vector_type(4))) short s16x4;
typedef __attribute__((ext_vector_type(4))) float f32x4;

typedef const __attribute__((address_space(1))) void GV;
typedef __attribute__((address_space(3))) void LV;

__device__ __forceinline__ short f2bf(float f) {
  union { float f; unsigned u; } v; v.f = f;
  unsigned r = v.u + 0x7fffu + ((v.u >> 16) & 1u);   // RNE
  return (short)(r >> 16);
}
__device__ __forceinline__ float b2f(short s) {
  union { float f; unsigned u; } v;
  v.u = ((unsigned)(unsigned short)s) << 16;
  return v.f;
}

// ---------------------------------------------------------------------------
// softmax over the 31-tap kernels: rows 0..15 = weight[h], row 16 = weight_f
__global__ void softmax_w(const float* __restrict__ w,
                          const float* __restrict__ wf,
                          float* __restrict__ wsm) {
  int t = threadIdx.x;
  if (t >= 17) return;
  const float* src = (t < 16) ? (w + t * KW_) : wf;
  float mx = -1e30f;
  #pragma unroll
  for (int k = 0; k < KW_; ++k) mx = fmaxf(mx, src[k]);
  float e[KW_], s = 0.f;
  #pragma unroll
  for (int k = 0; k < KW_; ++k) { e[k] = __expf(src[k] - mx); s += e[k]; }
  float inv = 1.f / s;
  #pragma unroll
  for (int k = 0; k < KW_; ++k) wsm[t * KW_ + k] = e[k] * inv;
}

// ---------------------------------------------------------------------------
// fp32 -> bf16 convert, vectorized x4
__global__ void cvt_bf16(const float* __restrict__ in, short* __restrict__ out, int n4) {
  int i = blockIdx.x * blockDim.x + threadIdx.x;
  if (i >= n4) return;
  float4 f = ((const float4*)in)[i];
  s16x4 s = { f2bf(f.x), f2bf(f.y), f2bf(f.z), f2bf(f.w) };
  ((s16x4*)out)[i] = s;
}

// W1 (2048x1024 fp32) -> W1b bf16 with ROW INTERLEAVE: row 2j = W1[j] (a), row 2j+1 = W1[1024+j] (g)
__global__ void cvt_w1i(const float* __restrict__ W1, short* __restrict__ W1b) {
  int idx = blockIdx.x * blockDim.x + threadIdx.x;  // 2048*1024/8 threads
  int r = idx >> 7;
  int c = (idx & 127) * 8;
  int s = (r & 1) ? (1024 + (r >> 1)) : (r >> 1);
  const float* src = W1 + (long)s * 1024 + c;
  bf16x8 o;
  #pragma unroll
  for (int i = 0; i < 8; ++i) o[i] = f2bf(src[i]);
  *(bf16x8*)(W1b + (long)r * 1024 + c) = o;
}

// copy W2[:, 0:1024] (fp32) -> W2b[:, 0:1024] (bf16), row stride 2048 both sides
__global__ void cvt_w2c(const float* __restrict__ W2, short* __restrict__ W2b) {
  int i = blockIdx.x * blockDim.x + threadIdx.x;   // over 1024*1024/4
  int o  = i >> 8;
  int c4 = (i & 255) * 4;
  float4 f = *(const float4*)(W2 + (long)o * K2_ + c4);
  s16x4 s = { f2bf(f.x), f2bf(f.y), f2bf(f.z), f2bf(f.w) };
  *(s16x4*)(W2b + (long)o * K2_ + c4) = s;
}

// fold the feature-axis conv into W2's second half:
// W2fold[o,j] = sum_k wf[k] * W2[o, 1024 + (j+15-k)]   (valid c only)
__global__ void fold_w2f(const float* __restrict__ W2,
                         const float* __restrict__ wsm,
                         short* __restrict__ W2b) {
  int idx = blockIdx.x * blockDim.x + threadIdx.x;   // over 1024*1024
  int o = idx >> 10, j = idx & 1023;
  const float* base = W2 + (long)o * K2_ + C_;
  float s = 0.f;
  #pragma unroll
  for (int k = 0; k < KW_; ++k) {
    int c = j + 15 - k;
    if (c >= 0 && c < C_) s += wsm[16 * KW_ + k] * base[c];
  }
  W2b[(long)o * K2_ + C_ + j] = f2bf(s);
}

// ---------------------------------------------------------------------------
// depthwise conv over time: xc[b,t,c] = sum_k w[c%16,k] * x[b,t+k-15,c]
__global__ __launch_bounds__(256) void conv_t_k(const short* __restrict__ A2in,
                                                const float* __restrict__ wsm,
                                                short* __restrict__ A2out) {
  const int tid = threadIdx.x;
  const int t0  = blockIdx.x * 128;
  const int c   = blockIdx.y * 256 + tid;
  const int b   = blockIdx.z;
  const int h   = c & (H_ - 1);

  float wk[KW_];
  #pragma unroll
  for (int k = 0; k < KW_; ++k) wk[k] = wsm[h * KW_ + k];

  const long rowbase = ((long)b * T_) * K2_ + C_ + c;
  float win[KW_];
  #pragma unroll
  for (int k = 0; k < 30; ++k) {
    int t = t0 - 15 + k;
    win[k] = (t >= 0 && t < T_) ? b2f(A2in[rowbase + (long)t * K2_]) : 0.f;
  }
  for (int tt = 0; tt < 128; ++tt) {
    int tl = t0 + tt + 15;
    win[30] = (tl < T_) ? b2f(A2in[rowbase + (long)tl * K2_]) : 0.f;
    float s = 0.f;
    #pragma unroll
    for (int k = 0; k < KW_; ++k) s = fmaf(wk[k], win[k], s);
    A2out[((long)b * T_ + t0 + tt) * K2_ + c] = f2bf(s);
    #pragma unroll
    for (int k = 0; k < 30; ++k) win[k] = win[k + 1];
  }
}

// ---------------------------------------------------------------------------
// 256x256 bf16 GEMM — 8-phase, r7's verified stage/vmcnt schedule, but with
// NO scheduling walls: ds_reads are plain C++ loads, so the compiler emits
// fine-grained counted lgkmcnt interleaved with the MFMAs (m97 behavior).
// Race safety WITHOUT lgkm(0):
//  - reads-before-overwrite: every read is consumed by a same-phase MFMA;
//    the HW can't issue that MFMA until the read retired (compiler waitcnt
//    before use), and the closing s_barrier is after the MFMAs -> a wave
//    passes it only with all its reads retired. Stages issue after that
//    barrier -> their LDS writes land after it. Safe.
//  - stage-before-read: counted VMW at P4/P8 + closing barrier precede the
//    dependent reads (next phase) -> cross-wave safe (r7-verified).
// Stage slots (iter i): P1,P2: A1<-t(2i+1) | P3,P4: B0<-t(2i+2) |
//                       P5,P6: A0<-t(2i+2) | P7,P8: B1<-t(2i+3)
// vmcnt(4) at P4 (retires B1',A1 = P5 deps) and P8 (retires B0,A0 = next-P1
// deps). Tail iter: stage A1 only, vmcnt(0)@P4.

// stage one half-tile (128 rows x 64 K) via 2 wave-wide global_load_lds
#define ST_H(GP, GR0, BUFS, REG, KT, HH) do { \
    _Pragma("unroll") \
    for (int i = 0; i < 2; ++i) { \
      int d = i * 8192 + tid * 16;   /* byte in 16KB half-region */ \
      int r = d >> 7; \
      int scb = (d & 127) ^ ((r & 7) << 4); \
      __builtin_amdgcn_global_load_lds( \
        (GV*)(GP + (long)(GR0 + (HH) * 128 + r) * K + (KT) * 64 + (scb >> 1)), \
        (LV*)&lds[(BUFS) + (REG) + (HH) * 8192 + (d >> 1)], 16, 0, 0); \
    } \
  } while (0)
#define ST_A(BUFS, KT, HH) ST_H(A,  arow0, BUFS, 0,     KT, HH)
#define ST_B(BUFS, KT, HH) ST_H(Bw, brow0, BUFS, 16384, KT, HH)

// read A m-pair Q (frags m=2Q,2Q+1; kk=0,1) from wave's half (wm)
#define RD_A(DST, BUFS, Q_) do { \
    _Pragma("unroll") \
    for (int mm = 0; mm < 2; ++mm) \
      _Pragma("unroll") \
      for (int kk = 0; kk < 2; ++kk) { \
        int r = (Q_) * 32 + mm * 16 + rlane; \
        int byt = (r * 128 + kk * 64 + klb) ^ ((r & 7) << 4); \
        DST[mm * 2 + kk] = *(const bf16x8*)&lds[(BUFS) + wm * 8192 + (byt >> 1)]; \
      } \
  } while (0)

// read all 4 B n-frags x 2 kk for the wave's 64-col panel
#define RD_B(DST, BUFS) do { \
    _Pragma("unroll") \
    for (int n = 0; n < 4; ++n) \
      _Pragma("unroll") \
      for (int kk = 0; kk < 2; ++kk) { \
        int row = wn * 64 + n * 16 + rlane; \
        int r = row & 127; \
        int byt = (r * 128 + kk * 64 + klb) ^ ((r & 7) << 4); \
        DST[n * 2 + kk] = *(const bf16x8*)&lds[(BUFS) + 16384 + (row >> 7) * 8192 + (byt >> 1)]; \
      } \
  } while (0)

// 16 MFMA: quadrant Q (m-pair) x 4 n x 2 kk
#define MM(AV, BV, Q_) do { \
    _Pragma("unroll") \
    for (int mm = 0; mm < 2; ++mm) \
      _Pragma("unroll") \
      for (int n = 0; n < 4; ++n) \
        _Pragma("unroll") \
        for (int kk = 0; kk < 2; ++kk) \
          acc[2 * (Q_) + mm][n] = __builtin_amdgcn_mfma_f32_16x16x32_bf16( \
              AV[mm * 2 + kk], BV[n * 2 + kk], acc[2 * (Q_) + mm][n], 0, 0, 0); \
  } while (0)

#define VMW(n_)  asm volatile("s_waitcnt vmcnt(" #n_ ")" ::: "memory")
// open: barrier then raise prio for the MFMA cluster (no lgkm wall!)
#define BARO() do { asm volatile("" ::: "memory"); __builtin_amdgcn_s_barrier(); \
                    __builtin_amdgcn_s_setprio(1); } while (0)
// close: drop prio, barrier
#define BARC() do { __builtin_amdgcn_s_setprio(0); \
                    asm volatile("" ::: "memory"); __builtin_amdgcn_s_barrier(); \
                    asm volatile("" ::: "memory"); } while (0)

template<int MODE>
__global__ __launch_bounds__(512, 2) void gemm256(const short* __restrict__ A,
                                                  const short* __restrict__ Bw,
                                                  const float* __restrict__ bias,
                                                  void* __restrict__ Cout,
                                                  int K, int NBN, int ldo) {
  __shared__ short lds[65536];   // 128 KB: 2 bufs x (A 32KB + B 32KB)
  const int tid  = threadIdx.x;
  const int lane = tid & 63;
  const int wave = tid >> 6;
  const int wm = wave >> 2, wn = wave & 3;

  // bijective XCD swizzle (nwg % 8 == 0 for both GEMMs)
  const int nwg = gridDim.x;
  const int wg  = (blockIdx.x & 7) * (nwg >> 3) + (blockIdx.x >> 3);
  const int bm = wg / NBN, bn = wg % NBN;
  const int arow0 = bm * 256, brow0 = bn * 256;

  const int rlane = lane & 15;
  const int klb   = (lane >> 4) * 16;   // byte offset of lane's k-slice

  f32x4 acc[8][4] = {};
  const int nt = K >> 6;                // 64-K tiles (even, >= 4)
  const int ni = nt >> 1;               // iterations of 2 tiles (>= 2)

  bf16x8 aF[4], bA[8], bB[8];

  // prologue: A0<-t0, B0<-t0, B1<-t1 (12 loads); keep B1's 4 in flight.
  ST_A(0, 0, 0); ST_A(0, 0, 1); ST_B(0, 0, 0); ST_B(0, 0, 1);
  ST_B(32768, 1, 0); ST_B(32768, 1, 1);
  VMW(4);
  asm volatile("" ::: "memory"); __builtin_amdgcn_s_barrier();

  for (int i = 0; i + 1 < ni; ++i) {
    const int kt1 = 2 * i + 1, kt2 = 2 * i + 2, kt3 = 2 * i + 3;
    /*P1*/ RD_A(aF, 0, 0); RD_B(bA, 0);     ST_A(32768, kt1, 0);          BARO(); MM(aF, bA, 0); BARC();
    /*P2*/ RD_A(aF, 0, 1);                  ST_A(32768, kt1, 1);          BARO(); MM(aF, bA, 1); BARC();
    /*P3*/ RD_A(aF, 0, 2);                  ST_B(0, kt2, 0);              BARO(); MM(aF, bA, 2); BARC();
    /*P4*/ RD_A(aF, 0, 3);                  ST_B(0, kt2, 1);     VMW(4);  BARO(); MM(aF, bA, 3); BARC();
    /*P5*/ RD_A(aF, 32768, 0); RD_B(bB, 32768); ST_A(0, kt2, 0);          BARO(); MM(aF, bB, 0); BARC();
    /*P6*/ RD_A(aF, 32768, 1);              ST_A(0, kt2, 1);              BARO(); MM(aF, bB, 1); BARC();
    /*P7*/ RD_A(aF, 32768, 2);              ST_B(32768, kt3, 0);          BARO(); MM(aF, bB, 2); BARC();
    /*P8*/ RD_A(aF, 32768, 3);              ST_B(32768, kt3, 1); VMW(4);  BARO(); MM(aF, bB, 3); BARC();
  }
  // tail iteration (tiles nt-2 in buf0, nt-1 in buf1): stage A1 only.
  /*P1*/ RD_A(aF, 0, 0); RD_B(bA, 0);       ST_A(32768, nt - 1, 0);       BARO(); MM(aF, bA, 0); BARC();
  /*P2*/ RD_A(aF, 0, 1);                    ST_A(32768, nt - 1, 1);       BARO(); MM(aF, bA, 1); BARC();
  /*P3*/ RD_A(aF, 0, 2);                                                  BARO(); MM(aF, bA, 2); BARC();
  /*P4*/ RD_A(aF, 0, 3);                                         VMW(0);  BARO(); MM(aF, bA, 3); BARC();
  /*P5*/ RD_A(aF, 32768, 0); RD_B(bB, 32768);                             BARO(); MM(aF, bB, 0); BARC();
  /*P6*/ RD_A(aF, 32768, 1);                                              BARO(); MM(aF, bB, 1); BARC();
  /*P7*/ RD_A(aF, 32768, 2);                                              BARO(); MM(aF, bB, 2); BARC();
  /*P8*/ RD_A(aF, 32768, 3);                                              BARO(); MM(aF, bB, 3);
  __builtin_amdgcn_s_setprio(0);

  // epilogue: C/D layout col = lane&15, row = (lane>>4)*4 + i
  #pragma unroll
  for (int m = 0; m < 8; ++m) {
    const int r = arow0 + wm * 128 + m * 16 + (lane >> 4) * 4;
    #pragma unroll
    for (int n = 0; n < 4; ++n) {
      const int c = brow0 + wn * 64 + n * 16 + (lane & 15);
      if (MODE == 0) {
        const float bb = bias[c];
        #pragma unroll
        for (int i = 0; i < 4; ++i)
          ((float*)Cout)[(long)(r + i) * ldo + c] = acc[m][n][i] + bb;
      } else {
        // interleaved: even c = a_{c/2}, odd c = g_{c/2}; GLU = a*sigmoid(g)
        const int oc = (c & 1) ? (1024 + (c >> 1)) : (c >> 1);
        const float bb = bias[oc];
        #pragma unroll
        for (int i = 0; i < 4; ++i) {
          float v = acc[m][n][i] + bb;
          float o = __shfl_xor(v, 1);    // partner lane holds the paired col
          if (!(c & 1))
            ((short*)Cout)[(long)(r + i) * ldo + 1024 + (c >> 1)] =
                f2bf(v / (1.f + __expf(-o)));
        }
      }
    }
  }
}

// ---------------------------------------------------------------------------
extern "C" void kernel_launch(void* const* d_in, const int* in_sizes, int n_in,
                              void* d_out, int out_size, void* d_ws, size_t ws_size,
                              hipStream_t stream) {
  const float* q   = (const float*)d_in[0];
  const float* W1  = (const float*)d_in[4];
  const float* b1  = (const float*)d_in[5];
  const float* W2  = (const float*)d_in[6];
  const float* b2  = (const float*)d_in[7];
  const float* wt  = (const float*)d_in[8];
  const float* wtf = (const float*)d_in[9];

  // workspace layout (bf16 as short), ~104 MB total
  short* Abf = (short*)d_ws;                       // 16384x1024
  short* W1b = Abf + (long)M_ * K1_;               // 2048x1024 interleaved
  short* W2b = W1b + (long)N1_ * K1_;              // 1024x2048 (B^T for GEMM2)
  short* A2  = W2b + (long)N2_ * K2_;              // 16384x2048: [xc | x]
  float* wsm = (float*)(A2 + (long)M_ * K2_);      // 17*31 softmaxed taps

  softmax_w<<<1, 64, 0, stream>>>(wt, wtf, wsm);

  cvt_bf16<<<(M_ * K1_ / 4) / 256, 256, 0, stream>>>(q, Abf, M_ * K1_ / 4);
  cvt_w1i<<<(N1_ * K1_ / 8) / 256, 256, 0, stream>>>(W1, W1b);
  cvt_w2c<<<(C_ * C_ / 4) / 256, 256, 0, stream>>>(W2, W2b);
  fold_w2f<<<(C_ * C_) / 256, 256, 0, stream>>>(W2, wsm, W2b);

  // GEMM1 + fused GLU: x -> A2[:, 1024:2048]
  gemm256<1><<<(M_ / 256) * (N1_ / 256), 512, 0, stream>>>(
      Abf, W1b, b1, A2, K1_, N1_ / 256, K2_);

  // time depthwise conv -> A2[:, 0:1024]
  conv_t_k<<<dim3(T_ / 128, C_ / 256, B_), 256, 0, stream>>>(A2, wsm, A2);

  // GEMM2: out = A2 @ W2b^T + b2 -> fp32
  gemm256<0><<<(M_ / 256) * (N2_ / 256), 512, 0, stream>>>(
      A2, W2b, b2, d_out, K2_, N2_ / 256, N2_);
}

// Round 9
// 239.109 us; speedup vs baseline: 1.0881x; 1.0881x over previous
//
#include <hip/hip_runtime.h>
#include <hip/hip_bf16.h>

// Problem constants
#define B_  16
#define T_  1024
#define C_  1024
#define H_  16
#define KW_ 31
#define M_  (B_ * T_)     // 16384 rows
#define N1_ (2 * C_)      // 2048  (GEMM1 N)
#define K1_ C_            // 1024  (GEMM1 K)
#define N2_ C_            // 1024  (GEMM2 N)
#define K2_ (2 * C_)      // 2048  (GEMM2 K)

typedef __attribute__((ext_vector_type(8))) short bf16x8;
typedef __attribute__((ext_vector_type(4))) short s16x4;
typedef __attribute__((ext_vector_type(4))) float f32x4;

typedef const __attribute__((address_space(1))) void GV;
typedef __attribute__((address_space(3))) void LV;

__device__ __forceinline__ short f2bf(float f) {
  union { float f; unsigned u; } v; v.f = f;
  unsigned r = v.u + 0x7fffu + ((v.u >> 16) & 1u);   // RNE
  return (short)(r >> 16);
}
__device__ __forceinline__ float b2f(short s) {
  union { float f; unsigned u; } v;
  v.u = ((unsigned)(unsigned short)s) << 16;
  return v.f;
}

// ---------------------------------------------------------------------------
// softmax over the 31-tap kernels: rows 0..15 = weight[h], row 16 = weight_f
__global__ void softmax_w(const float* __restrict__ w,
                          const float* __restrict__ wf,
                          float* __restrict__ wsm) {
  int t = threadIdx.x;
  if (t >= 17) return;
  const float* src = (t < 16) ? (w + t * KW_) : wf;
  float mx = -1e30f;
  #pragma unroll
  for (int k = 0; k < KW_; ++k) mx = fmaxf(mx, src[k]);
  float e[KW_], s = 0.f;
  #pragma unroll
  for (int k = 0; k < KW_; ++k) { e[k] = __expf(src[k] - mx); s += e[k]; }
  float inv = 1.f / s;
  #pragma unroll
  for (int k = 0; k < KW_; ++k) wsm[t * KW_ + k] = e[k] * inv;
}

// ---------------------------------------------------------------------------
// fp32 -> bf16 convert, vectorized x4
__global__ void cvt_bf16(const float* __restrict__ in, short* __restrict__ out, int n4) {
  int i = blockIdx.x * blockDim.x + threadIdx.x;
  if (i >= n4) return;
  float4 f = ((const float4*)in)[i];
  s16x4 s = { f2bf(f.x), f2bf(f.y), f2bf(f.z), f2bf(f.w) };
  ((s16x4*)out)[i] = s;
}

// W1 (2048x1024 fp32) -> W1b bf16 with ROW INTERLEAVE: row 2j = W1[j] (a), row 2j+1 = W1[1024+j] (g)
__global__ void cvt_w1i(const float* __restrict__ W1, short* __restrict__ W1b) {
  int idx = blockIdx.x * blockDim.x + threadIdx.x;  // 2048*1024/8 threads
  int r = idx >> 7;
  int c = (idx & 127) * 8;
  int s = (r & 1) ? (1024 + (r >> 1)) : (r >> 1);
  const float* src = W1 + (long)s * 1024 + c;
  bf16x8 o;
  #pragma unroll
  for (int i = 0; i < 8; ++i) o[i] = f2bf(src[i]);
  *(bf16x8*)(W1b + (long)r * 1024 + c) = o;
}

// copy W2[:, 0:1024] (fp32) -> W2b[:, 0:1024] (bf16), row stride 2048 both sides
__global__ void cvt_w2c(const float* __restrict__ W2, short* __restrict__ W2b) {
  int i = blockIdx.x * blockDim.x + threadIdx.x;   // over 1024*1024/4
  int o  = i >> 8;
  int c4 = (i & 255) * 4;
  float4 f = *(const float4*)(W2 + (long)o * K2_ + c4);
  s16x4 s = { f2bf(f.x), f2bf(f.y), f2bf(f.z), f2bf(f.w) };
  *(s16x4*)(W2b + (long)o * K2_ + c4) = s;
}

// fold the feature-axis conv into W2's second half:
// W2fold[o,j] = sum_k wf[k] * W2[o, 1024 + (j+15-k)]   (valid c only)
__global__ void fold_w2f(const float* __restrict__ W2,
                         const float* __restrict__ wsm,
                         short* __restrict__ W2b) {
  int idx = blockIdx.x * blockDim.x + threadIdx.x;   // over 1024*1024
  int o = idx >> 10, j = idx & 1023;
  const float* base = W2 + (long)o * K2_ + C_;
  float s = 0.f;
  #pragma unroll
  for (int k = 0; k < KW_; ++k) {
    int c = j + 15 - k;
    if (c >= 0 && c < C_) s += wsm[16 * KW_ + k] * base[c];
  }
  W2b[(long)o * K2_ + C_ + j] = f2bf(s);
}

// ---------------------------------------------------------------------------
// depthwise conv over time: xc[b,t,c] = sum_k w[c%16,k] * x[b,t+k-15,c]
__global__ __launch_bounds__(256) void conv_t_k(const short* __restrict__ A2in,
                                                const float* __restrict__ wsm,
                                                short* __restrict__ A2out) {
  const int tid = threadIdx.x;
  const int t0  = blockIdx.x * 128;
  const int c   = blockIdx.y * 256 + tid;
  const int b   = blockIdx.z;
  const int h   = c & (H_ - 1);

  float wk[KW_];
  #pragma unroll
  for (int k = 0; k < KW_; ++k) wk[k] = wsm[h * KW_ + k];

  const long rowbase = ((long)b * T_) * K2_ + C_ + c;
  float win[KW_];
  #pragma unroll
  for (int k = 0; k < 30; ++k) {
    int t = t0 - 15 + k;
    win[k] = (t >= 0 && t < T_) ? b2f(A2in[rowbase + (long)t * K2_]) : 0.f;
  }
  for (int tt = 0; tt < 128; ++tt) {
    int tl = t0 + tt + 15;
    win[30] = (tl < T_) ? b2f(A2in[rowbase + (long)tl * K2_]) : 0.f;
    float s = 0.f;
    #pragma unroll
    for (int k = 0; k < KW_; ++k) s = fmaf(wk[k], win[k], s);
    A2out[((long)b * T_ + t0 + tt) * K2_ + c] = f2bf(s);
    #pragma unroll
    for (int k = 0; k < 30; ++k) win[k] = win[k + 1];
  }
}

// ---------------------------------------------------------------------------
// 128x128 bf16 GEMM, BK=64 double-buffered, 64KB LDS -> 2 blocks/CU (4
// waves/SIMD). 8 waves (2M x 4N -> 64x32 per wave). 4 phases / 2 K-tiles;
// same-phase reads (compiler emits counted lgkm), r7-style audited stage
// slots + counted vmcnt; cross-BLOCK overlap supplies the latency hiding.
// Slots (iter i, kt1=2i+1, kt2=2i+2, kt3=2i+3):
//   P1: A1<-kt1 | P2: B0<-kt2, VMW(2) | P3: A0<-kt2 | P4: B1<-kt3, VMW(2)
// Reads: P1,P2 read buf0 (t 2i); P3,P4 read buf1 (t 2i+1).
// VMW audit (2 loads/slot/thread): @P2 outstanding {B1'(2),A1(2),B0(2)}=6,
// retire 4 -> B1',A1 = exactly P3's deps; @P4 {B0,A0,B1}=6, retire 4 ->
// B0,A0 = next-P1's deps. Barrier follows each VMW before dependent reads
// -> cross-wave safe. Overwrite safety: each region's last reader consumed
// its reads in the PRECEDING phase (MFMA before that phase's closing bar).
// Swizzle: byte ^= (row&7)<<4, row stride 128B; linear LDS dest +
// inverse-swizzled GLOBAL source + swizzled read (rule 21).

// stage one 64-row half (8KB) of a 128x64 region; 1 load/thread
#define ST_H(GP, GR0, BUFS, REG, KT, HH) do { \
    int d = tid * 16;                  /* byte in 8KB half */ \
    int rr_ = (HH) * 64 + (d >> 7);    /* row in 128-row region */ \
    int scb = (d & 127) ^ ((rr_ & 7) << 4); \
    __builtin_amdgcn_global_load_lds( \
      (GV*)(GP + (long)(GR0 + rr_) * K + (KT) * 64 + (scb >> 1)), \
      (LV*)&lds[(BUFS) + (REG) + (HH) * 4096 + (d >> 1)], 16, 0, 0); \
  } while (0)
#define ST_A(BUFS, KT) do { ST_H(A,  arow0, BUFS, 0,    KT, 0); \
                            ST_H(A,  arow0, BUFS, 0,    KT, 1); } while (0)
#define ST_B(BUFS, KT) do { ST_H(Bw, brow0, BUFS, 8192, KT, 0); \
                            ST_H(Bw, brow0, BUFS, 8192, KT, 1); } while (0)

// read A m-pair MP (m = 2*MP+mm; kk=0,1): 4 x ds_read_b128
#define RD_A2(DST, BUFS, MP) do { \
    _Pragma("unroll") \
    for (int mm = 0; mm < 2; ++mm) \
      _Pragma("unroll") \
      for (int kk = 0; kk < 2; ++kk) { \
        int r = wm * 64 + ((MP) * 2 + mm) * 16 + rlane; \
        int byt = (r * 128 + kk * 64 + klb) ^ ((r & 7) << 4); \
        DST[mm * 2 + kk] = *(const bf16x8*)&lds[(BUFS) + (byt >> 1)]; \
      } \
  } while (0)

// read the wave's 2 B n-frags x 2 kk: 4 x ds_read_b128
#define RD_B(DST, BUFS) do { \
    _Pragma("unroll") \
    for (int n = 0; n < 2; ++n) \
      _Pragma("unroll") \
      for (int kk = 0; kk < 2; ++kk) { \
        int r = wn * 32 + n * 16 + rlane; \
        int byt = (r * 128 + kk * 64 + klb) ^ ((r & 7) << 4); \
        DST[n * 2 + kk] = *(const bf16x8*)&lds[(BUFS) + 8192 + (byt >> 1)]; \
      } \
  } while (0)

// 8 MFMA: m-pair MP x 2 n x 2 kk
#define MM(AV, BV, MP) do { \
    _Pragma("unroll") \
    for (int mm = 0; mm < 2; ++mm) \
      _Pragma("unroll") \
      for (int n = 0; n < 2; ++n) \
        _Pragma("unroll") \
        for (int kk = 0; kk < 2; ++kk) \
          acc[2 * (MP) + mm][n] = __builtin_amdgcn_mfma_f32_16x16x32_bf16( \
              AV[mm * 2 + kk], BV[n * 2 + kk], acc[2 * (MP) + mm][n], 0, 0, 0); \
  } while (0)

#define VMW(n_)  asm volatile("s_waitcnt vmcnt(" #n_ ")" ::: "memory")
#define BARO() do { asm volatile("" ::: "memory"); __builtin_amdgcn_s_barrier(); \
                    __builtin_amdgcn_s_setprio(1); } while (0)
#define BARC() do { __builtin_amdgcn_s_setprio(0); \
                    asm volatile("" ::: "memory"); __builtin_amdgcn_s_barrier(); \
                    asm volatile("" ::: "memory"); } while (0)

template<int MODE>
__global__ __launch_bounds__(512, 4) void gemm128(const short* __restrict__ A,
                                                  const short* __restrict__ Bw,
                                                  const float* __restrict__ bias,
                                                  void* __restrict__ Cout,
                                                  int K, int NBN, int ldo) {
  __shared__ short lds[32768];   // 64 KB: 2 bufs x (A 16KB + B 16KB)
  const int tid  = threadIdx.x;
  const int lane = tid & 63;
  const int wave = tid >> 6;
  const int wm = wave >> 2, wn = wave & 3;

  // bijective XCD swizzle (nwg % 8 == 0 for both GEMMs)
  const int nwg = gridDim.x;
  const int wg  = (blockIdx.x & 7) * (nwg >> 3) + (blockIdx.x >> 3);
  const int bm = wg / NBN, bn = wg % NBN;
  const int arow0 = bm * 128, brow0 = bn * 128;

  const int rlane = lane & 15;
  const int klb   = (lane >> 4) * 16;   // byte offset of lane's k-slice

  f32x4 acc[4][2] = {};
  const int nt = K >> 6;                // 64-K tiles (even, >= 4)
  const int ni = nt >> 1;               // iterations of 2 tiles (>= 2)

  bf16x8 aF[4], bA[4], bB[4];

  // prologue: A0,B0 <- t0 (4 loads), B1 <- t1 (2); retire A0,B0, keep B1.
  ST_A(0, 0); ST_B(0, 0);
  ST_B(16384, 1);
  VMW(2);
  asm volatile("" ::: "memory"); __builtin_amdgcn_s_barrier();

  for (int i = 0; i + 1 < ni; ++i) {
    const int kt1 = 2 * i + 1, kt2 = 2 * i + 2, kt3 = 2 * i + 3;
    /*P1*/ RD_B(bA, 0); RD_A2(aF, 0, 0);         ST_A(16384, kt1);          BARO(); MM(aF, bA, 0); BARC();
    /*P2*/ RD_A2(aF, 0, 1);                      ST_B(0, kt2);     VMW(2);  BARO(); MM(aF, bA, 1); BARC();
    /*P3*/ RD_B(bB, 16384); RD_A2(aF, 16384, 0); ST_A(0, kt2);              BARO(); MM(aF, bB, 0); BARC();
    /*P4*/ RD_A2(aF, 16384, 1);                  ST_B(16384, kt3); VMW(2);  BARO(); MM(aF, bB, 1); BARC();
  }
  // tail iteration (tiles nt-2 in buf0, nt-1 in buf1): stage A1 only.
  /*P1*/ RD_B(bA, 0); RD_A2(aF, 0, 0);           ST_A(16384, nt - 1);       BARO(); MM(aF, bA, 0); BARC();
  /*P2*/ RD_A2(aF, 0, 1);                                           VMW(0); BARO(); MM(aF, bA, 1); BARC();
  /*P3*/ RD_B(bB, 16384); RD_A2(aF, 16384, 0);                              BARO(); MM(aF, bB, 0); BARC();
  /*P4*/ RD_A2(aF, 16384, 1);                                               BARO(); MM(aF, bB, 1);
  __builtin_amdgcn_s_setprio(0);

  // epilogue: C/D layout col = lane&15, row = (lane>>4)*4 + i
  #pragma unroll
  for (int m = 0; m < 4; ++m) {
    const int r = arow0 + wm * 64 + m * 16 + (lane >> 4) * 4;
    #pragma unroll
    for (int n = 0; n < 2; ++n) {
      const int c = brow0 + wn * 32 + n * 16 + (lane & 15);
      if (MODE == 0) {
        const float bb = bias[c];
        #pragma unroll
        for (int i = 0; i < 4; ++i)
          ((float*)Cout)[(long)(r + i) * ldo + c] = acc[m][n][i] + bb;
      } else {
        // interleaved: even c = a_{c/2}, odd c = g_{c/2}; GLU = a*sigmoid(g)
        const int oc = (c & 1) ? (1024 + (c >> 1)) : (c >> 1);
        const float bb = bias[oc];
        #pragma unroll
        for (int i = 0; i < 4; ++i) {
          float v = acc[m][n][i] + bb;
          float o = __shfl_xor(v, 1);    // partner lane holds the paired col
          if (!(c & 1))
            ((short*)Cout)[(long)(r + i) * ldo + 1024 + (c >> 1)] =
                f2bf(v / (1.f + __expf(-o)));
        }
      }
    }
  }
}

// ---------------------------------------------------------------------------
extern "C" void kernel_launch(void* const* d_in, const int* in_sizes, int n_in,
                              void* d_out, int out_size, void* d_ws, size_t ws_size,
                              hipStream_t stream) {
  const float* q   = (const float*)d_in[0];
  const float* W1  = (const float*)d_in[4];
  const float* b1  = (const float*)d_in[5];
  const float* W2  = (const float*)d_in[6];
  const float* b2  = (const float*)d_in[7];
  const float* wt  = (const float*)d_in[8];
  const float* wtf = (const float*)d_in[9];

  // workspace layout (bf16 as short), ~104 MB total
  short* Abf = (short*)d_ws;                       // 16384x1024
  short* W1b = Abf + (long)M_ * K1_;               // 2048x1024 interleaved
  short* W2b = W1b + (long)N1_ * K1_;              // 1024x2048 (B^T for GEMM2)
  short* A2  = W2b + (long)N2_ * K2_;              // 16384x2048: [xc | x]
  float* wsm = (float*)(A2 + (long)M_ * K2_);      // 17*31 softmaxed taps

  softmax_w<<<1, 64, 0, stream>>>(wt, wtf, wsm);

  cvt_bf16<<<(M_ * K1_ / 4) / 256, 256, 0, stream>>>(q, Abf, M_ * K1_ / 4);
  cvt_w1i<<<(N1_ * K1_ / 8) / 256, 256, 0, stream>>>(W1, W1b);
  cvt_w2c<<<(C_ * C_ / 4) / 256, 256, 0, stream>>>(W2, W2b);
  fold_w2f<<<(C_ * C_) / 256, 256, 0, stream>>>(W2, wsm, W2b);

  // GEMM1 + fused GLU: x -> A2[:, 1024:2048]
  gemm128<1><<<(M_ / 128) * (N1_ / 128), 512, 0, stream>>>(
      Abf, W1b, b1, A2, K1_, N1_ / 128, K2_);

  // time depthwise conv -> A2[:, 0:1024]
  conv_t_k<<<dim3(T_ / 128, C_ / 256, B_), 256, 0, stream>>>(A2, wsm, A2);

  // GEMM2: out = A2 @ W2b^T + b2 -> fp32
  gemm128<0><<<(M_ / 128) * (N2_ / 128), 512, 0, stream>>>(
      A2, W2b, b2, d_out, K2_, N2_ / 128, N2_);
}